// Round 17
// baseline (774.502 us; speedup 1.0000x reference)
//
#include <hip/hip_runtime.h>

#define T_PTS 100000
#define NB 2
#define NROWS (NB * T_PTS)
#define GCELLS 32768
#define NCELL (NB * GCELLS)
#define HID 128
#define MBLK 64
#define GRID_RB (NROWS / MBLK) /* 3125, exact */

typedef __attribute__((ext_vector_type(8))) short bf16x8;
typedef __attribute__((ext_vector_type(16))) float f32x16;

#define MFMA32 __builtin_amdgcn_mfma_f32_32x32x16_bf16

__device__ __forceinline__ unsigned short bf16rne(float f) {
  unsigned u = __float_as_uint(f);
  return (unsigned short)((u + 0x7FFFu + ((u >> 16) & 1u)) >> 16);
}
__device__ __forceinline__ void bf16split(float f, unsigned short& h,
                                          unsigned short& l) {
  h = bf16rne(f);
  l = bf16rne(f - __uint_as_float(((unsigned)h) << 16));
}
__device__ __forceinline__ unsigned packhl(float f) {
  unsigned short h, l;
  bf16split(f, h, l);
  return (((unsigned)h) << 16) | (unsigned)l;
}

union U8 { bf16x8 v; unsigned u[4]; };

__device__ __forceinline__ void up2(unsigned w0, unsigned w1, unsigned& h,
                                    unsigned& l) {
  h = __builtin_amdgcn_perm(w1, w0, 0x07060302u);
  l = __builtin_amdgcn_perm(w1, w0, 0x05040100u);
}

// per-half relu: zero each 16-bit half of (qh,ql) where qh's half-sign is set
__device__ __forceinline__ void relu2(unsigned qh, unsigned ql, unsigned& rh,
                                      unsigned& rl) {
  const unsigned keep = ((~qh >> 15) & 0x00010001u) * 0xFFFFu;
  rh = qh & keep;
  rl = ql & keep;
}

__device__ __forceinline__ void dma16(const unsigned* g, unsigned* l) {
  __builtin_amdgcn_global_load_lds(
      (const __attribute__((address_space(1))) unsigned*)g,
      (__attribute__((address_space(3))) unsigned*)l, 16, 0, 0);
}

// ---------------------------------------------------------------------------
// net stored CSR-permuted (R13); activation row = [hi 64 u32][lo 64 u32].
//
// 32x32x16 MFMA resnet block (R16/R14 schedule, half the MFMA instructions).
// 64 rows/block, 4 waves; wave owns 64 rows x 32 cols = 2 row-tiles (rt) of
// 32x32. Per K-step (K=32): 2 kh x 2 rt x (3+3) = 24 MFMA32 (was 48 MFMA16).
// A-frag (32x32x16): lane l elem j = A[rt*32+(l&31)][kh*16+(l>>5)*8+j]; read
// from the SAME LDS slot layout as before: mt = rt*2+((l>>4)&1),
// kq = kh*2+(l>>5), addr = sb + mt*256 + (kq*16+(l&15))*4 (b128, linear).
// C/D: col = wc*32+(l&31), row = rt*32+(r&3)+8*(r>>2)+4*(l>>5)  [m74/m101].
// h stored as hi/lo u16 planes in 32x32-A-frag order: write (row,c) at
// ((((c>>4)*2+rt)*64 + (row&31)+32*((c>>3)&1))*8 + (c&7)); read collapses to
// lane-linear b128 at ((ksh2*2+rt)*64+l)*8.
// ---------------------------------------------------------------------------
template <int MODE>
__global__ __launch_bounds__(256, 4) void resblock_mfma(
    const void* __restrict__ srcv, const float* __restrict__ posw,
    const float* __restrict__ posb, const unsigned* __restrict__ cell,
    const int* __restrict__ perm, const int* __restrict__ vcell,
    const unsigned short* __restrict__ w0p, const float* __restrict__ b0,
    const unsigned short* __restrict__ w1p, const float* __restrict__ b1,
    const unsigned short* __restrict__ swp, unsigned* __restrict__ net_out) {
  __shared__ unsigned lds32[8192];  // 32 KB; K-loop uses 16 KB; h aliases all
  const int tid = threadIdx.x;
  const int lane = tid & 63;
  const int wid = tid >> 6;
  const int wc = wid;
  const int t0 = blockIdx.x * MBLK;

  const int srow = wid * 16 + (lane & 15);
  const int skc4 = (lane >> 4) * 4;
  const long vrow = (long)t0 + srow;
  const unsigned* nrowL = nullptr;
  const unsigned* crowL = nullptr;
  float pp0 = 0.f, pp1 = 0.f, pp2 = 0.f;
  if (MODE == 1) {
    nrowL = (const unsigned*)srcv + vrow * HID;
    crowL = cell + (long)vcell[vrow] * HID;
  } else {
    const float* ppp = (const float*)srcv + (long)perm[vrow] * 3;
    pp0 = ppp[0]; pp1 = ppp[1]; pp2 = ppp[2];
  }

  auto stage_dma = [&](int ks) {
    unsigned* base = &lds32[((ks & 1) << 11) + wid * 256];
    const unsigned* rowp = (ks < 4) ? nrowL : crowL;
    const int ko = ((ks & 3) << 4) + skc4;
    dma16(rowp + ko, base);              // xh plane
    dma16(rowp + 64 + ko, base + 1024);  // xl plane
  };
  auto stage0 = [&](int ks) {  // MODE 0: compute + split -> 2 planes
    const int kb = ks * 32 + (lane >> 4) * 8;
    float xv[8];
#pragma unroll
    for (int i = 0; i < 8; i += 4) {
      float4 wa = *(const float4*)(posw + kb + i);
      float4 wb = *(const float4*)(posw + 256 + kb + i);
      float4 wcc = *(const float4*)(posw + 512 + kb + i);
      float4 bb = *(const float4*)(posb + kb + i);
      xv[i + 0] = fmaf(pp0, wa.x, fmaf(pp1, wb.x, fmaf(pp2, wcc.x, bb.x)));
      xv[i + 1] = fmaf(pp0, wa.y, fmaf(pp1, wb.y, fmaf(pp2, wcc.y, bb.y)));
      xv[i + 2] = fmaf(pp0, wa.z, fmaf(pp1, wb.z, fmaf(pp2, wcc.z, bb.z)));
      xv[i + 3] = fmaf(pp0, wa.w, fmaf(pp1, wb.w, fmaf(pp2, wcc.w, bb.w)));
    }
    unsigned ph[8];
#pragma unroll
    for (int i = 0; i < 8; ++i) ph[i] = packhl(xv[i]);
    uint4 xh4, xl4;
    up2(ph[0], ph[1], xh4.x, xl4.x);
    up2(ph[2], ph[3], xh4.y, xl4.y);
    up2(ph[4], ph[5], xh4.z, xl4.z);
    up2(ph[6], ph[7], xh4.w, xl4.w);
    const int db = ((ks & 1) << 11) + wid * 256 + lane * 4;
    *(uint4*)&lds32[db] = xh4;
    *(uint4*)&lds32[db + 1024] = xl4;
  };
  // load B frags for one GEMM at K-step ks: kh=0,1 (hi+lo planes)
  auto load_B = [&](const unsigned short* base, int loOff, int ks, bf16x8* h,
                    bf16x8* l) {
#pragma unroll
    for (int kh = 0; kh < 2; ++kh) {
      const int fi = ((ks * 2 + kh) * 4 + wc) * 512 + lane * 8;
      h[kh] = *(const bf16x8*)(base + fi);
      l[kh] = *(const bf16x8*)(base + loOff + fi);
    }
  };

  f32x16 accy[2], acco[2];
#pragma unroll
  for (int i = 0; i < 2; ++i) {
#pragma unroll
    for (int j = 0; j < 16; ++j) { accy[i][j] = 0.f; acco[i][j] = 0.f; }
  }

  bf16x8 b1h[2], b1l[2], b2h[2], b2l[2];
  if (MODE == 1) {
    stage_dma(0);
  } else {
    stage0(0);
  }
  load_B(w0p, 32768, 0, b1h, b1l);  // B1(0) prefetch overlaps staging
  __syncthreads();

  const int amt0 = (lane >> 4) & 1;  // region offset within rt
  const int akq0 = lane >> 5;        // k-quad offset within kh
  const int ari = lane & 15;

#pragma unroll 1
  for (int ks = 0; ks < 8; ++ks) {
    const int sb = (ks & 1) << 11;
    load_B(swp, 32768, ks, b2h, b2l);            // B2(ks): phase1 covers it
    if (MODE == 1 && ks < 7) stage_dma(ks + 1);  // DMA rides everything
    // phase 1: accy += relu(x) @ w0   (B1 resident -> no vmem wait)
    __builtin_amdgcn_s_setprio(1);
#pragma unroll
    for (int rt = 0; rt < 2; ++rt) {
#pragma unroll
      for (int kh = 0; kh < 2; ++kh) {
        const unsigned* px = &lds32[sb + (rt * 2 + amt0) * 256 +
                                    ((kh * 2 + akq0) * 16 + ari) * 4];
        U8 xh, xl, rh, rl;
        xh.v = *(const bf16x8*)px;
        xl.v = *(const bf16x8*)(px + 1024);
#pragma unroll
        for (int i = 0; i < 4; ++i) relu2(xh.u[i], xl.u[i], rh.u[i], rl.u[i]);
        accy[rt] = MFMA32(rh.v, b1h[kh], accy[rt], 0, 0, 0);
        accy[rt] = MFMA32(rh.v, b1l[kh], accy[rt], 0, 0, 0);
        accy[rt] = MFMA32(rl.v, b1h[kh], accy[rt], 0, 0, 0);
      }
    }
    __builtin_amdgcn_s_setprio(0);
    asm volatile("" ::: "memory");  // keep phase2's A re-reads (no CSE)
    if (ks < 7) load_B(w0p, 32768, ks + 1, b1h, b1l);  // B1(ks+1) in place
    // phase 2: acco += x @ sw   (B2 covered by phase1; B1-next rides)
    __builtin_amdgcn_s_setprio(1);
#pragma unroll
    for (int rt = 0; rt < 2; ++rt) {
#pragma unroll
      for (int kh = 0; kh < 2; ++kh) {
        const unsigned* px = &lds32[sb + (rt * 2 + amt0) * 256 +
                                    ((kh * 2 + akq0) * 16 + ari) * 4];
        bf16x8 xh = *(const bf16x8*)px;
        bf16x8 xl = *(const bf16x8*)(px + 1024);
        acco[rt] = MFMA32(xh, b2h[kh], acco[rt], 0, 0, 0);
        acco[rt] = MFMA32(xh, b2l[kh], acco[rt], 0, 0, 0);
        acco[rt] = MFMA32(xl, b2h[kh], acco[rt], 0, 0, 0);
      }
    }
    __builtin_amdgcn_s_setprio(0);
    if (MODE == 0 && ks < 7) stage0(ks + 1);
    __syncthreads();
  }

  const int cCol = wc * 32 + (lane & 31);
  // h = relu(y + b0) -> hi/lo u16 planes in 32x32-A-frag order (aliases x)
  {
    const float b0v = b0[cCol];
    const int jj = cCol & 7;                 // == lane & 7
    const int sbit = ((lane >> 3) & 1) << 5; // == ((cCol>>3)&1) << 5
    unsigned short* hb = (unsigned short*)lds32;
#pragma unroll
    for (int rt = 0; rt < 2; ++rt) {
      const int f = (cCol >> 4) * 2 + rt;
#pragma unroll
      for (int r = 0; r < 16; ++r) {
        const int row31 = (r & 3) + 8 * (r >> 2) + 4 * (lane >> 5);
        float h = fmaxf(accy[rt][r] + b0v, 0.f);
        unsigned short hh, hl;
        bf16split(h, hh, hl);
        const int o = (f * 64 + row31 + sbit) * 8 + jj;
        hb[o] = hh;
        hb[8192 + o] = hl;
      }
    }
  }
  __syncthreads();

  // GEMM2: acco += h @ w1  (lane-linear b128 A reads, zero unpack)
  {
    const unsigned short* hb = (const unsigned short*)lds32;
#pragma unroll
    for (int ksh2 = 0; ksh2 < 8; ++ksh2) {
      bf16x8 ch, cl;
      {
        const int fi = (ksh2 * 4 + wc) * 512 + lane * 8;
        ch = *(const bf16x8*)(w1p + fi);
        cl = *(const bf16x8*)(w1p + 16384 + fi);
      }
      __builtin_amdgcn_s_setprio(1);
#pragma unroll
      for (int rt = 0; rt < 2; ++rt) {
        const int o = ((ksh2 * 2 + rt) * 64 + lane) * 8;
        bf16x8 ah = *(const bf16x8*)(hb + o);
        bf16x8 al = *(const bf16x8*)(hb + 8192 + o);
        acco[rt] = MFMA32(ah, ch, acco[rt], 0, 0, 0);
        acco[rt] = MFMA32(ah, cl, acco[rt], 0, 0, 0);
        acco[rt] = MFMA32(al, ch, acco[rt], 0, 0, 0);
      }
      __builtin_amdgcn_s_setprio(0);
    }
  }

  // epilogue: split once, store to hi|lo planes (u16 stores)
  {
    const float b1v = b1[cCol];
#pragma unroll
    for (int rt = 0; rt < 2; ++rt) {
#pragma unroll
      for (int r = 0; r < 16; ++r) {
        const int row = rt * 32 + (r & 3) + 8 * (r >> 2) + 4 * (lane >> 5);
        unsigned short* op =
            (unsigned short*)(net_out + ((long)t0 + row) * HID);
        unsigned short h, l;
        bf16split(acco[rt][r] + b1v, h, l);
        op[cCol] = h;
        op[128 + cCol] = l;
      }
    }
  }
}

// ---------------------------------------------------------------------------
// final: c = net @ fc_c_w + fc_c_b, fp32 written IN-PLACE over plane rows.
// 32x32x16 MFMA, K=128, double-buffered slots of K=32.
// ---------------------------------------------------------------------------
__global__ __launch_bounds__(256, 4) void final_mfma(
    unsigned* __restrict__ net, const unsigned short* __restrict__ wcp,
    const float* __restrict__ bc) {
  __shared__ unsigned lds32[4096];
  const int tid = threadIdx.x;
  const int lane = tid & 63;
  const int wid = tid >> 6;
  const int wc = wid;
  const int t0 = blockIdx.x * MBLK;

  const int srow = wid * 16 + (lane & 15);
  const int skc4 = (lane >> 4) * 4;
  const unsigned* nrowL = net + ((long)t0 + srow) * HID;

  auto stage = [&](int ks) {
    unsigned* base = &lds32[((ks & 1) << 11) + wid * 256];
    const int ko = (ks << 4) + skc4;
    dma16(nrowL + ko, base);
    dma16(nrowL + 64 + ko, base + 1024);
  };
  auto load_B = [&](int ks, bf16x8* h, bf16x8* l) {
#pragma unroll
    for (int kh = 0; kh < 2; ++kh) {
      const int fi = ((ks * 2 + kh) * 4 + wc) * 512 + lane * 8;
      h[kh] = *(const bf16x8*)(wcp + fi);
      l[kh] = *(const bf16x8*)(wcp + 16384 + fi);
    }
  };

  f32x16 acc[2];
#pragma unroll
  for (int i = 0; i < 2; ++i) {
#pragma unroll
    for (int j = 0; j < 16; ++j) acc[i][j] = 0.f;
  }

  bf16x8 ch[2], cl[2];
  stage(0);
  load_B(0, ch, cl);
  __syncthreads();

  const int amt0 = (lane >> 4) & 1;
  const int akq0 = lane >> 5;
  const int ari = lane & 15;

#pragma unroll 1
  for (int ks = 0; ks < 4; ++ks) {
    const int sb = (ks & 1) << 11;
    if (ks < 3) stage(ks + 1);
    __builtin_amdgcn_s_setprio(1);
#pragma unroll
    for (int rt = 0; rt < 2; ++rt) {
      const unsigned* px0 = &lds32[sb + (rt * 2 + amt0) * 256 +
                                   ((0 * 2 + akq0) * 16 + ari) * 4];
      bf16x8 xh = *(const bf16x8*)px0;
      bf16x8 xl = *(const bf16x8*)(px0 + 1024);
      acc[rt] = MFMA32(xh, ch[0], acc[rt], 0, 0, 0);
      acc[rt] = MFMA32(xh, cl[0], acc[rt], 0, 0, 0);
      acc[rt] = MFMA32(xl, ch[0], acc[rt], 0, 0, 0);
    }
    __builtin_amdgcn_s_setprio(0);
    bf16x8 sh = ch[1], sl = cl[1];
    if (ks < 3) load_B(ks + 1, ch, cl);  // B(ks+1) rides through kh=1 MFMAs
    __builtin_amdgcn_s_setprio(1);
#pragma unroll
    for (int rt = 0; rt < 2; ++rt) {
      const unsigned* px1 = &lds32[sb + (rt * 2 + amt0) * 256 +
                                   ((1 * 2 + akq0) * 16 + ari) * 4];
      bf16x8 xh = *(const bf16x8*)px1;
      bf16x8 xl = *(const bf16x8*)(px1 + 1024);
      acc[rt] = MFMA32(xh, sh, acc[rt], 0, 0, 0);
      acc[rt] = MFMA32(xh, sl, acc[rt], 0, 0, 0);
      acc[rt] = MFMA32(xl, sh, acc[rt], 0, 0, 0);
    }
    __builtin_amdgcn_s_setprio(0);
    __syncthreads();
  }

  float* fout = (float*)net;
  const int cCol = wc * 32 + (lane & 31);
  const float bcv = bc[cCol];
#pragma unroll
  for (int rt = 0; rt < 2; ++rt) {
#pragma unroll
    for (int r = 0; r < 16; ++r) {
      const int row = rt * 32 + (r & 3) + 8 * (r >> 2) + 4 * (lane >> 5);
      fout[((long)t0 + row) * HID + cCol] = acc[rt][r] + bcv;
    }
  }
}

// ---------------------------------------------------------------------------
// one-time weight pack: fp32 (K,128) -> bf16 hi/lo planes in 32x32-B-frag
// order: frag (ksh=k>>4, nt=n>>5): lane (n&31)|(((k>>3)&1)<<5), elem k&7.
// ---------------------------------------------------------------------------
__global__ void pack_weights(const float* __restrict__ fc0,
                             const float* __restrict__ fc1,
                             const float* __restrict__ sc,
                             const float* __restrict__ fcc,
                             unsigned short* __restrict__ w0p,
                             unsigned short* __restrict__ w1p,
                             unsigned short* __restrict__ swp,
                             unsigned short* __restrict__ wcp) {
  int gid = blockIdx.x * 256 + threadIdx.x;
  const float* src;
  unsigned short* dst;
  int K, e;
  if (gid < 163840) { src = fc0; dst = w0p; K = 256; e = gid; }
  else if (gid < 327680) { src = sc; dst = swp; K = 256; e = gid - 163840; }
  else if (gid < 409600) { src = fc1; dst = w1p; K = 128; e = gid - 327680; }
  else if (gid < 425984) { src = fcc; dst = wcp; K = 128; e = gid - 409600; }
  else return;
  const int mat = e / (K * 128);
  const int r = e - mat * K * 128;
  const int k = r >> 7, n = r & 127;
  const float x = src[e];
  unsigned short hi, lo;
  bf16split(x, hi, lo);
  const int ksh = k >> 4, nt = n >> 5;
  const int l = (n & 31) | (((k >> 3) & 1) << 5);
  const int j = k & 7;
  unsigned short* mb = dst + (long)mat * K * 256;
  const int off = ((ksh * 4 + nt) * 64 + l) * 8 + j;
  mb[off] = hi;
  mb[off + K * 128] = lo;
}

// --------------------------- CSR build -------------------------------------
__global__ void zero_i32(int* __restrict__ p, int n) {
  const int i = blockIdx.x * 256 + threadIdx.x;
  if (i < n) p[i] = 0;
}

__global__ void count_csr(const int* __restrict__ idx, int* __restrict__ curs) {
  const int gid = blockIdx.x * 256 + threadIdx.x;
  if (gid >= NROWS) return;
  const int b = gid / T_PTS;
  atomicAdd(&curs[b * GCELLS + idx[gid]], 1);
}

__global__ __launch_bounds__(1024) void scan_csr(const int* __restrict__ cnt,
                                                 int* __restrict__ offsets) {
  __shared__ int part[1024];
  const int t = threadIdx.x;
  const int base = t * (NCELL / 1024);
  int s = 0;
  for (int i = 0; i < NCELL / 1024; ++i) s += cnt[base + i];
  part[t] = s;
  __syncthreads();
  for (int d = 1; d < 1024; d <<= 1) {
    int v = (t >= d) ? part[t - d] : 0;
    __syncthreads();
    part[t] += v;
    __syncthreads();
  }
  int run = (t == 0) ? 0 : part[t - 1];
  for (int i = 0; i < NCELL / 1024; ++i) {
    offsets[base + i] = run;
    run += cnt[base + i];
  }
  if (t == 1023) offsets[NCELL] = run;
}

__global__ void scatter_csr(const int* __restrict__ idx,
                            const int* __restrict__ offsets,
                            int* __restrict__ curs, int* __restrict__ perm,
                            int* __restrict__ vcell) {
  const int gid = blockIdx.x * 256 + threadIdx.x;
  if (gid >= NROWS) return;
  const int b = gid / T_PTS;
  const int cellk = b * GCELLS + idx[gid];
  const int slot = offsets[cellk] + atomicAdd(&curs[cellk], 1);
  perm[slot] = gid;
  vcell[slot] = cellk;
}

// ------------------- CSR segmented reductions (contiguous rows) ------------
__global__ __launch_bounds__(256) void pool_csr(const unsigned* __restrict__ net,
                                                const int* __restrict__ offsets,
                                                unsigned* __restrict__ cellf) {
  const int cellk = blockIdx.x * 4 + (threadIdx.x >> 6);
  const int lane = threadIdx.x & 63;
  const int s0 = offsets[cellk], s1 = offsets[cellk + 1];
  if (s0 >= s1) return;
  float m0 = -3.402823466e38f, m1 = -3.402823466e38f;
  unsigned h0 = 0u, l0 = 0u, h1 = 0u, l1 = 0u;
  for (int row = s0; row < s1; ++row) {
    const unsigned* rp = net + (long)row * HID;
    unsigned hi = rp[lane];
    unsigned lo = rp[64 + lane];
    float v0 = __uint_as_float(hi << 16) + __uint_as_float(lo << 16);
    float v1 = __uint_as_float(hi & 0xFFFF0000u) +
               __uint_as_float(lo & 0xFFFF0000u);
    if (v0 > m0) { m0 = v0; h0 = hi; l0 = lo; }
    if (v1 > m1) { m1 = v1; h1 = hi; l1 = lo; }
  }
  unsigned* cp = cellf + (long)cellk * HID;
  cp[lane] = (h0 & 0xFFFFu) | (h1 & 0xFFFF0000u);
  cp[64 + lane] = (l0 & 0xFFFFu) | (l1 & 0xFFFF0000u);
}

// ---------------------------------------------------------------------------
// FUSED cellsum + mean + transpose (R16): 64 cells/block, register row-sums,
// padded-LDS transpose, coalesced out writes. Bit-identical to cellsum+mean.
// ---------------------------------------------------------------------------
__global__ __launch_bounds__(256) void cellsum_mean(
    const float* __restrict__ c, const int* __restrict__ offsets,
    float* __restrict__ out) {
  __shared__ float ts[64][129];
  __shared__ float cf[64];
  const int t = threadIdx.x;
  const int b = blockIdx.x >> 9;  // 512 blocks per batch (32768/64)
  const int g0 = (blockIdx.x & 511) * 64;
  const int cell0 = b * GCELLS + g0;
  {
    const int ci = t >> 2;
    const int c0 = (t & 3) * 32;
    const int s0 = offsets[cell0 + ci], s1 = offsets[cell0 + ci + 1];
    float acc[32];
#pragma unroll
    for (int j = 0; j < 32; ++j) acc[j] = 0.f;
    for (int row = s0; row < s1; ++row) {
      const float* rp = c + (long)row * HID + c0;
#pragma unroll
      for (int j = 0; j < 32; j += 4) {
        float4 v = *(const float4*)(rp + j);
        acc[j + 0] += v.x;
        acc[j + 1] += v.y;
        acc[j + 2] += v.z;
        acc[j + 3] += v.w;
      }
    }
#pragma unroll
    for (int j = 0; j < 32; ++j) ts[ci][c0 + j] = acc[j];
    if ((t & 3) == 0) cf[ci] = (float)(s1 - s0);
  }
  __syncthreads();
  const int lane = t & 63;
  const int w = t >> 6;
  float* ob = out + (long)b * HID * GCELLS + g0 + lane;
  const float cnt = cf[lane];
  const bool nz = cnt > 0.f;
  const float inv = nz ? 1.0f / cnt : 0.f;
#pragma unroll 4
  for (int cc = w; cc < HID; cc += 4) {
    float v = ts[lane][cc] * inv;
    ob[(long)cc * GCELLS] = nz ? v : 0.f;
  }
}

extern "C" void kernel_launch(void* const* d_in, const int* in_sizes, int n_in,
                              void* d_out, int out_size, void* d_ws,
                              size_t ws_size, hipStream_t stream) {
  const float* points = (const float*)d_in[0];
  const int* idx = (const int*)d_in[1];
  const float* fc_pos_w = (const float*)d_in[2];
  const float* fc_pos_b = (const float*)d_in[3];
  const float* fc0_w = (const float*)d_in[4];
  const float* fc0_b = (const float*)d_in[5];
  const float* fc1_w = (const float*)d_in[6];
  const float* fc1_b = (const float*)d_in[7];
  const float* sc_w = (const float*)d_in[8];
  const float* fc_c_w = (const float*)d_in[9];
  const float* fc_c_b = (const float*)d_in[10];
  float* out = (float*)d_out;

  const long NET_BYTES = (long)NROWS * HID * 4;         // 102,400,000
  const long CELL_BYTES = (long)NCELL * HID * 4;        // 33,554,432
  unsigned* net = (unsigned*)d_ws;                      // permuted plane rows
  unsigned* cellf = (unsigned*)((char*)d_ws + NET_BYTES);
  int* offsets = (int*)((char*)d_ws + NET_BYTES + CELL_BYTES);  // 65537 ints

  // scratch in d_out's dead region (overwritten by cellsum_mean at the end)
  unsigned short* packs = (unsigned short*)d_out;
  unsigned short* w0p = packs;            // 5 * 65536
  unsigned short* swp = packs + 327680;   // 5 * 65536
  unsigned short* w1p = packs + 655360;   // 5 * 32768
  unsigned short* wcp = packs + 819200;   // 32768
  int* curs = (int*)((char*)d_out + (2l << 20));
  int* perm = (int*)((char*)d_out + (3l << 20));
  int* vcell = (int*)((char*)d_out + (4l << 20));

  const int GRID_PTS = (NROWS + 255) / 256;       // 782
  const int GRID_ZERO = (NCELL + 255) / 256;      // 256
  const int GRID_CELL = NCELL / 4;                // 16384
  const int GRID_CM = NCELL / 64;                 // 1024

  pack_weights<<<1664, 256, 0, stream>>>(fc0_w, fc1_w, sc_w, fc_c_w, w0p, w1p,
                                         swp, wcp);

  zero_i32<<<GRID_ZERO, 256, 0, stream>>>(curs, NCELL);
  count_csr<<<GRID_PTS, 256, 0, stream>>>(idx, curs);
  scan_csr<<<1, 1024, 0, stream>>>(curs, offsets);
  zero_i32<<<GRID_ZERO, 256, 0, stream>>>(curs, NCELL);
  scatter_csr<<<GRID_PTS, 256, 0, stream>>>(idx, offsets, curs, perm, vcell);

  resblock_mfma<0><<<GRID_RB, 256, 0, stream>>>(
      points, fc_pos_w, fc_pos_b, nullptr, perm, vcell, w0p, fc0_b, w1p,
      fc1_b, swp, net);

  for (int i = 1; i < 5; ++i) {
    pool_csr<<<GRID_CELL, 256, 0, stream>>>(net, offsets, cellf);
    resblock_mfma<1><<<GRID_RB, 256, 0, stream>>>(
        net, nullptr, nullptr, cellf, perm, vcell, w0p + (long)i * 65536,
        fc0_b + i * HID, w1p + (long)i * 32768, fc1_b + i * HID,
        swp + (long)i * 65536, net);
  }

  final_mfma<<<GRID_RB, 256, 0, stream>>>(net, wcp, fc_c_b);
  cellsum_mean<<<GRID_CM, 256, 0, stream>>>((const float*)net, offsets, out);
}

// Round 18
// 719.348 us; speedup vs baseline: 1.0767x; 1.0767x over previous
//
#include <hip/hip_runtime.h>

#define T_PTS 100000
#define NB 2
#define NROWS (NB * T_PTS)
#define GCELLS 32768
#define NCELL (NB * GCELLS)
#define HID 128
#define MBLK 64
#define GRID_RB (NROWS / MBLK) /* 3125, exact */

typedef __attribute__((ext_vector_type(8))) short bf16x8;
typedef __attribute__((ext_vector_type(4))) float f32x4;

#define MFMA16 __builtin_amdgcn_mfma_f32_16x16x32_bf16

__device__ __forceinline__ unsigned short bf16rne(float f) {
  unsigned u = __float_as_uint(f);
  return (unsigned short)((u + 0x7FFFu + ((u >> 16) & 1u)) >> 16);
}
__device__ __forceinline__ void bf16split(float f, unsigned short& h,
                                          unsigned short& l) {
  h = bf16rne(f);
  l = bf16rne(f - __uint_as_float(((unsigned)h) << 16));
}
__device__ __forceinline__ unsigned packhl(float f) {
  unsigned short h, l;
  bf16split(f, h, l);
  return (((unsigned)h) << 16) | (unsigned)l;
}

union U8 { bf16x8 v; unsigned u[4]; };

__device__ __forceinline__ void up2(unsigned w0, unsigned w1, unsigned& h,
                                    unsigned& l) {
  h = __builtin_amdgcn_perm(w1, w0, 0x07060302u);
  l = __builtin_amdgcn_perm(w1, w0, 0x05040100u);
}

// per-half relu: zero each 16-bit half of (qh,ql) where qh's half-sign is set
__device__ __forceinline__ void relu2(unsigned qh, unsigned ql, unsigned& rh,
                                      unsigned& rl) {
  const unsigned keep = ((~qh >> 15) & 0x00010001u) * 0xFFFFu;
  rh = qh & keep;
  rl = ql & keep;
}

__device__ __forceinline__ void dma16(const unsigned* g, unsigned* l) {
  __builtin_amdgcn_global_load_lds(
      (const __attribute__((address_space(1))) unsigned*)g,
      (__attribute__((address_space(3))) unsigned*)l, 16, 0, 0);
}

// ---------------------------------------------------------------------------
// net stored in CSR-permuted order (R13); activation row = hi|lo bf16 planes.
//
// Fused resnet block (R14/R16 structure - best measured). 64 rows/block,
// 4 waves, each wave 64 rows x 32 cols. Zero-extra-reg B1 prefetch:
//   phase1 (accy, B1(ks) resident) -> load_B(w0p,ks+1) into dead b1 regs ->
//   phase2 (acco, B2(ks) covered by phase1) -> barrier.
// ---------------------------------------------------------------------------
template <int MODE>
__global__ __launch_bounds__(256, 4) void resblock_mfma(
    const void* __restrict__ srcv, const float* __restrict__ posw,
    const float* __restrict__ posb, const unsigned* __restrict__ cell,
    const int* __restrict__ perm, const int* __restrict__ vcell,
    const unsigned short* __restrict__ w0p, const float* __restrict__ b0,
    const unsigned short* __restrict__ w1p, const float* __restrict__ b1,
    const unsigned short* __restrict__ swp, unsigned* __restrict__ net_out) {
  __shared__ unsigned lds32[8192];  // 32 KB; K-loop uses 16 KB; h aliases all
  const int tid = threadIdx.x;
  const int lane = tid & 63;
  const int wid = tid >> 6;
  const int wc = wid;
  const int t0 = blockIdx.x * MBLK;

  const int srow = wid * 16 + (lane & 15);
  const int skc4 = (lane >> 4) * 4;
  const long vrow = (long)t0 + srow;
  const unsigned* nrowL = nullptr;
  const unsigned* crowL = nullptr;
  float pp0 = 0.f, pp1 = 0.f, pp2 = 0.f;
  if (MODE == 1) {
    nrowL = (const unsigned*)srcv + vrow * HID;
    crowL = cell + (long)vcell[vrow] * HID;
  } else {
    const float* ppp = (const float*)srcv + (long)perm[vrow] * 3;
    pp0 = ppp[0]; pp1 = ppp[1]; pp2 = ppp[2];
  }

  auto stage_dma = [&](int ks) {
    unsigned* base = &lds32[((ks & 1) << 11) + wid * 256];
    const unsigned* rowp = (ks < 4) ? nrowL : crowL;
    const int ko = ((ks & 3) << 4) + skc4;
    dma16(rowp + ko, base);              // xh plane
    dma16(rowp + 64 + ko, base + 1024);  // xl plane
  };
  auto stage0 = [&](int ks) {  // MODE 0: compute + split -> 2 planes
    const int kb = ks * 32 + (lane >> 4) * 8;
    float xv[8];
#pragma unroll
    for (int i = 0; i < 8; i += 4) {
      float4 wa = *(const float4*)(posw + kb + i);
      float4 wb = *(const float4*)(posw + 256 + kb + i);
      float4 wcc = *(const float4*)(posw + 512 + kb + i);
      float4 bb = *(const float4*)(posb + kb + i);
      xv[i + 0] = fmaf(pp0, wa.x, fmaf(pp1, wb.x, fmaf(pp2, wcc.x, bb.x)));
      xv[i + 1] = fmaf(pp0, wa.y, fmaf(pp1, wb.y, fmaf(pp2, wcc.y, bb.y)));
      xv[i + 2] = fmaf(pp0, wa.z, fmaf(pp1, wb.z, fmaf(pp2, wcc.z, bb.z)));
      xv[i + 3] = fmaf(pp0, wa.w, fmaf(pp1, wb.w, fmaf(pp2, wcc.w, bb.w)));
    }
    unsigned ph[8];
#pragma unroll
    for (int i = 0; i < 8; ++i) ph[i] = packhl(xv[i]);
    uint4 xh4, xl4;
    up2(ph[0], ph[1], xh4.x, xl4.x);
    up2(ph[2], ph[3], xh4.y, xl4.y);
    up2(ph[4], ph[5], xh4.z, xl4.z);
    up2(ph[6], ph[7], xh4.w, xl4.w);
    const int db = ((ks & 1) << 11) + wid * 256 + lane * 4;
    *(uint4*)&lds32[db] = xh4;
    *(uint4*)&lds32[db + 1024] = xl4;
  };
  auto load_B = [&](const unsigned short* base, int loOff, int ks, bf16x8* h,
                    bf16x8* l) {
#pragma unroll
    for (int nt = 0; nt < 2; ++nt) {
      const int fi = (ks * 8 + wc * 2 + nt) * 512 + lane * 8;
      h[nt] = *(const bf16x8*)(base + fi);
      l[nt] = *(const bf16x8*)(base + loOff + fi);
    }
  };

  f32x4 accy[4][2], acco[4][2];
#pragma unroll
  for (int i = 0; i < 4; ++i)
#pragma unroll
    for (int j = 0; j < 2; ++j) {
      f32x4 z = {0.f, 0.f, 0.f, 0.f};
      accy[i][j] = z;
      acco[i][j] = z;
    }

  bf16x8 b1h[2], b1l[2], b2h[2], b2l[2];
  if (MODE == 1) {
    stage_dma(0);
  } else {
    stage0(0);
  }
  load_B(w0p, 32768, 0, b1h, b1l);  // B1(0) prefetch overlaps staging
  __syncthreads();

#pragma unroll 1
  for (int ks = 0; ks < 8; ++ks) {
    const int sb = (ks & 1) << 11;
    load_B(swp, 32768, ks, b2h, b2l);            // B2(ks): phase1 covers it
    if (MODE == 1 && ks < 7) stage_dma(ks + 1);  // DMA rides everything
    // phase 1: accy += relu(x) @ w0   (B1 already resident -> no vmem wait)
    __builtin_amdgcn_s_setprio(1);
#pragma unroll
    for (int mt = 0; mt < 4; ++mt) {
      const unsigned* px = &lds32[sb + mt * 256 + lane * 4];
      U8 xh, xl, rh, rl;
      xh.v = *(const bf16x8*)px;
      xl.v = *(const bf16x8*)(px + 1024);
#pragma unroll
      for (int i = 0; i < 4; ++i) relu2(xh.u[i], xl.u[i], rh.u[i], rl.u[i]);
#pragma unroll
      for (int nt = 0; nt < 2; ++nt) {
        accy[mt][nt] = MFMA16(rh.v, b1h[nt], accy[mt][nt], 0, 0, 0);
        accy[mt][nt] = MFMA16(rh.v, b1l[nt], accy[mt][nt], 0, 0, 0);
        accy[mt][nt] = MFMA16(rl.v, b1h[nt], accy[mt][nt], 0, 0, 0);
      }
    }
    __builtin_amdgcn_s_setprio(0);
    asm volatile("" ::: "memory");  // keep phase2's A re-reads (no CSE)
    if (ks < 7) load_B(w0p, 32768, ks + 1, b1h, b1l);  // B1(ks+1) in place
    // phase 2: acco += x @ sw   (B2 covered by phase1; B1-next rides)
    __builtin_amdgcn_s_setprio(1);
#pragma unroll
    for (int mt = 0; mt < 4; ++mt) {
      const unsigned* px = &lds32[sb + mt * 256 + lane * 4];
      bf16x8 xh = *(const bf16x8*)px;
      bf16x8 xl = *(const bf16x8*)(px + 1024);
#pragma unroll
      for (int nt = 0; nt < 2; ++nt) {
        acco[mt][nt] = MFMA16(xh, b2h[nt], acco[mt][nt], 0, 0, 0);
        acco[mt][nt] = MFMA16(xh, b2l[nt], acco[mt][nt], 0, 0, 0);
        acco[mt][nt] = MFMA16(xl, b2h[nt], acco[mt][nt], 0, 0, 0);
      }
    }
    __builtin_amdgcn_s_setprio(0);
    if (MODE == 0 && ks < 7) stage0(ks + 1);
    __syncthreads();
  }

  // h = relu(y + b0) -> packed u32 in frag order (aliases x area), swizzled
  {
    float b0v[2];
#pragma unroll
    for (int nt = 0; nt < 2; ++nt)
      b0v[nt] = b0[wc * 32 + nt * 16 + (lane & 15)];
#pragma unroll
    for (int mt = 0; mt < 4; ++mt) {
#pragma unroll
      for (int nt = 0; nt < 2; ++nt) {
        const int c = wc * 32 + nt * 16 + (lane & 15);
        const int k2 = c >> 5;
        const int j = c & 7;
        const int lahi = ((c & 31) >> 3) * 16;
#pragma unroll
        for (int r = 0; r < 4; ++r) {
          float h = fmaxf(accy[mt][nt][r] + b0v[nt], 0.f);
          int la = lahi + (lane >> 4) * 4 + r;
          la ^= (la >> 3) & 7;
          lds32[((k2 * 4 + mt) * 64 + la) * 8 + j] = packhl(h);
        }
      }
    }
  }
  __syncthreads();

  // GEMM2: acco += h @ w1 (packed h read + in-reg unpack)
  {
    const int lar2 = lane ^ ((lane >> 3) & 7);
#pragma unroll
    for (int k2 = 0; k2 < 4; ++k2) {
      bf16x8 ch[2], cl[2];
      load_B(w1p, 16384, k2, ch, cl);
      __builtin_amdgcn_s_setprio(1);
#pragma unroll
      for (int mt = 0; mt < 4; ++mt) {
        const unsigned* p = &lds32[((k2 * 4 + mt) * 64 + lar2) * 8];
        uint4 q1 = *(const uint4*)p;
        uint4 q2 = *(const uint4*)(p + 4);
        unsigned q[8] = {q1.x, q1.y, q1.z, q1.w, q2.x, q2.y, q2.z, q2.w};
        U8 ah, al;
#pragma unroll
        for (int p2 = 0; p2 < 4; ++p2)
          up2(q[2 * p2], q[2 * p2 + 1], ah.u[p2], al.u[p2]);
#pragma unroll
        for (int nt = 0; nt < 2; ++nt) {
          acco[mt][nt] = MFMA16(ah.v, ch[nt], acco[mt][nt], 0, 0, 0);
          acco[mt][nt] = MFMA16(ah.v, cl[nt], acco[mt][nt], 0, 0, 0);
          acco[mt][nt] = MFMA16(al.v, ch[nt], acco[mt][nt], 0, 0, 0);
        }
      }
      __builtin_amdgcn_s_setprio(0);
    }
  }

  // epilogue: split once, store to hi|lo planes (u16 stores); all rows valid
  {
    float b1v[2];
#pragma unroll
    for (int nt = 0; nt < 2; ++nt)
      b1v[nt] = b1[wc * 32 + nt * 16 + (lane & 15)];
#pragma unroll
    for (int mt = 0; mt < 4; ++mt) {
#pragma unroll
      for (int r = 0; r < 4; ++r) {
        const int row = mt * 16 + (lane >> 4) * 4 + r;
        unsigned short* op =
            (unsigned short*)(net_out + ((long)t0 + row) * HID);
        unsigned short h, l;
        bf16split(acco[mt][0][r] + b1v[0], h, l);
        op[wc * 32 + (lane & 15)] = h;
        op[128 + wc * 32 + (lane & 15)] = l;
        bf16split(acco[mt][1][r] + b1v[1], h, l);
        op[wc * 32 + 16 + (lane & 15)] = h;
        op[128 + wc * 32 + 16 + (lane & 15)] = l;
      }
    }
  }
}

// ---------------------------------------------------------------------------
// final: c = net @ fc_c_w + fc_c_b, fp32 written IN-PLACE over plane rows.
// B(ks+1) prefetched mid-cluster (R14 structure).
// ---------------------------------------------------------------------------
__global__ __launch_bounds__(256, 4) void final_mfma(
    unsigned* __restrict__ net, const unsigned short* __restrict__ wcp,
    const float* __restrict__ bc) {
  __shared__ unsigned lds32[4096];
  const int tid = threadIdx.x;
  const int lane = tid & 63;
  const int wid = tid >> 6;
  const int wc = wid;
  const int t0 = blockIdx.x * MBLK;

  const int srow = wid * 16 + (lane & 15);
  const int skc4 = (lane >> 4) * 4;
  const unsigned* nrowL = net + ((long)t0 + srow) * HID;

  auto stage = [&](int ks) {
    unsigned* base = &lds32[((ks & 1) << 11) + wid * 256];
    const int ko = (ks << 4) + skc4;
    dma16(nrowL + ko, base);
    dma16(nrowL + 64 + ko, base + 1024);
  };
  auto load_B = [&](int ks, bf16x8* h, bf16x8* l) {
#pragma unroll
    for (int nt = 0; nt < 2; ++nt) {
      const int fi = (ks * 8 + wc * 2 + nt) * 512 + lane * 8;
      h[nt] = *(const bf16x8*)(wcp + fi);
      l[nt] = *(const bf16x8*)(wcp + 16384 + fi);
    }
  };

  f32x4 acc[4][2];
#pragma unroll
  for (int i = 0; i < 4; ++i)
#pragma unroll
    for (int j = 0; j < 2; ++j) {
      f32x4 z = {0.f, 0.f, 0.f, 0.f};
      acc[i][j] = z;
    }

  bf16x8 ch[2], cl[2];
  stage(0);
  load_B(0, ch, cl);
  __syncthreads();

#pragma unroll 1
  for (int ks = 0; ks < 4; ++ks) {
    const int sb = (ks & 1) << 11;
    if (ks < 3) stage(ks + 1);
    __builtin_amdgcn_s_setprio(1);
#pragma unroll
    for (int mt = 0; mt < 2; ++mt) {
      const unsigned* px = &lds32[sb + mt * 256 + lane * 4];
      bf16x8 xh = *(const bf16x8*)px;
      bf16x8 xl = *(const bf16x8*)(px + 1024);
#pragma unroll
      for (int nt = 0; nt < 2; ++nt) {
        acc[mt][nt] = MFMA16(xh, ch[nt], acc[mt][nt], 0, 0, 0);
        acc[mt][nt] = MFMA16(xh, cl[nt], acc[mt][nt], 0, 0, 0);
        acc[mt][nt] = MFMA16(xl, ch[nt], acc[mt][nt], 0, 0, 0);
      }
    }
    __builtin_amdgcn_s_setprio(0);
    bf16x8 sh[2], sl[2];
#pragma unroll
    for (int nt = 0; nt < 2; ++nt) { sh[nt] = ch[nt]; sl[nt] = cl[nt]; }
    if (ks < 3) load_B(ks + 1, ch, cl);  // B(ks+1) rides through mt 2..3
    __builtin_amdgcn_s_setprio(1);
#pragma unroll
    for (int mt = 2; mt < 4; ++mt) {
      const unsigned* px = &lds32[sb + mt * 256 + lane * 4];
      bf16x8 xh = *(const bf16x8*)px;
      bf16x8 xl = *(const bf16x8*)(px + 1024);
#pragma unroll
      for (int nt = 0; nt < 2; ++nt) {
        acc[mt][nt] = MFMA16(xh, sh[nt], acc[mt][nt], 0, 0, 0);
        acc[mt][nt] = MFMA16(xh, sl[nt], acc[mt][nt], 0, 0, 0);
        acc[mt][nt] = MFMA16(xl, sh[nt], acc[mt][nt], 0, 0, 0);
      }
    }
    __builtin_amdgcn_s_setprio(0);
    __syncthreads();
  }

  float* fout = (float*)net;
  float bcv[2];
#pragma unroll
  for (int nt = 0; nt < 2; ++nt)
    bcv[nt] = bc[wc * 32 + nt * 16 + (lane & 15)];
#pragma unroll
  for (int mt = 0; mt < 4; ++mt) {
#pragma unroll
    for (int r = 0; r < 4; ++r) {
      const int row = mt * 16 + (lane >> 4) * 4 + r;
      float* op = fout + ((long)t0 + row) * HID;
      op[wc * 32 + (lane & 15)] = acc[mt][0][r] + bcv[0];
      op[wc * 32 + 16 + (lane & 15)] = acc[mt][1][r] + bcv[1];
    }
  }
}

// ---------------------------------------------------------------------------
// one-time weight pack: fp32 (K,128) -> bf16 hi/lo planes in MFMA-B-frag order
// ---------------------------------------------------------------------------
__global__ void pack_weights(const float* __restrict__ fc0,
                             const float* __restrict__ fc1,
                             const float* __restrict__ sc,
                             const float* __restrict__ fcc,
                             unsigned short* __restrict__ w0p,
                             unsigned short* __restrict__ w1p,
                             unsigned short* __restrict__ swp,
                             unsigned short* __restrict__ wcp) {
  int gid = blockIdx.x * 256 + threadIdx.x;
  const float* src;
  unsigned short* dst;
  int K, e;
  if (gid < 163840) { src = fc0; dst = w0p; K = 256; e = gid; }
  else if (gid < 327680) { src = sc; dst = swp; K = 256; e = gid - 163840; }
  else if (gid < 409600) { src = fc1; dst = w1p; K = 128; e = gid - 327680; }
  else if (gid < 425984) { src = fcc; dst = wcp; K = 128; e = gid - 409600; }
  else return;
  const int mat = e / (K * 128);
  const int r = e - mat * K * 128;
  const int k = r >> 7, n = r & 127;
  const float x = src[e];
  unsigned short hi, lo;
  bf16split(x, hi, lo);
  const int ks = k >> 5, lg = (k >> 3) & 3, j = k & 7;
  const int l = lg * 16 + (n & 15), nt = n >> 4;
  unsigned short* mb = dst + (long)mat * K * 256;
  const int off = ((ks * 8 + nt) * 64 + l) * 8 + j;
  mb[off] = hi;
  mb[off + K * 128] = lo;
}

// --------------------------- CSR build -------------------------------------
__global__ void zero_i32(int* __restrict__ p, int n) {
  const int i = blockIdx.x * 256 + threadIdx.x;
  if (i < n) p[i] = 0;
}

__global__ void count_csr(const int* __restrict__ idx, int* __restrict__ curs) {
  const int gid = blockIdx.x * 256 + threadIdx.x;
  if (gid >= NROWS) return;
  const int b = gid / T_PTS;
  atomicAdd(&curs[b * GCELLS + idx[gid]], 1);
}

__global__ __launch_bounds__(1024) void scan_csr(const int* __restrict__ cnt,
                                                 int* __restrict__ offsets) {
  __shared__ int part[1024];
  const int t = threadIdx.x;
  const int base = t * (NCELL / 1024);
  int s = 0;
  for (int i = 0; i < NCELL / 1024; ++i) s += cnt[base + i];
  part[t] = s;
  __syncthreads();
  for (int d = 1; d < 1024; d <<= 1) {
    int v = (t >= d) ? part[t - d] : 0;
    __syncthreads();
    part[t] += v;
    __syncthreads();
  }
  int run = (t == 0) ? 0 : part[t - 1];
  for (int i = 0; i < NCELL / 1024; ++i) {
    offsets[base + i] = run;
    run += cnt[base + i];
  }
  if (t == 1023) offsets[NCELL] = run;
}

__global__ void scatter_csr(const int* __restrict__ idx,
                            const int* __restrict__ offsets,
                            int* __restrict__ curs, int* __restrict__ perm,
                            int* __restrict__ vcell) {
  const int gid = blockIdx.x * 256 + threadIdx.x;
  if (gid >= NROWS) return;
  const int b = gid / T_PTS;
  const int cellk = b * GCELLS + idx[gid];
  const int slot = offsets[cellk] + atomicAdd(&curs[cellk], 1);
  perm[slot] = gid;
  vcell[slot] = cellk;
}

// ------------------- CSR segmented reductions (contiguous rows) ------------
__global__ __launch_bounds__(256) void pool_csr(const unsigned* __restrict__ net,
                                                const int* __restrict__ offsets,
                                                unsigned* __restrict__ cellf) {
  const int cellk = blockIdx.x * 4 + (threadIdx.x >> 6);
  const int lane = threadIdx.x & 63;
  const int s0 = offsets[cellk], s1 = offsets[cellk + 1];
  if (s0 >= s1) return;
  float m0 = -3.402823466e38f, m1 = -3.402823466e38f;
  unsigned h0 = 0u, l0 = 0u, h1 = 0u, l1 = 0u;
  for (int row = s0; row < s1; ++row) {
    const unsigned* rp = net + (long)row * HID;
    unsigned hi = rp[lane];
    unsigned lo = rp[64 + lane];
    float v0 = __uint_as_float(hi << 16) + __uint_as_float(lo << 16);
    float v1 = __uint_as_float(hi & 0xFFFF0000u) +
               __uint_as_float(lo & 0xFFFF0000u);
    if (v0 > m0) { m0 = v0; h0 = hi; l0 = lo; }
    if (v1 > m1) { m1 = v1; h1 = hi; l1 = lo; }
  }
  unsigned* cp = cellf + (long)cellk * HID;
  cp[lane] = (h0 & 0xFFFFu) | (h1 & 0xFFFF0000u);
  cp[64 + lane] = (l0 & 0xFFFFu) | (l1 & 0xFFFF0000u);
}

// ---------------------------------------------------------------------------
// FUSED cellsum + mean + transpose (R16): 64 cells/block, register row-sums,
// padded-LDS transpose, coalesced out writes. Bit-identical to cellsum+mean.
// ---------------------------------------------------------------------------
__global__ __launch_bounds__(256) void cellsum_mean(
    const float* __restrict__ c, const int* __restrict__ offsets,
    float* __restrict__ out) {
  __shared__ float ts[64][129];
  __shared__ float cf[64];
  const int t = threadIdx.x;
  const int b = blockIdx.x >> 9;  // 512 blocks per batch (32768/64)
  const int g0 = (blockIdx.x & 511) * 64;
  const int cell0 = b * GCELLS + g0;
  {
    const int ci = t >> 2;
    const int c0 = (t & 3) * 32;
    const int s0 = offsets[cell0 + ci], s1 = offsets[cell0 + ci + 1];
    float acc[32];
#pragma unroll
    for (int j = 0; j < 32; ++j) acc[j] = 0.f;
    for (int row = s0; row < s1; ++row) {
      const float* rp = c + (long)row * HID + c0;
#pragma unroll
      for (int j = 0; j < 32; j += 4) {
        float4 v = *(const float4*)(rp + j);
        acc[j + 0] += v.x;
        acc[j + 1] += v.y;
        acc[j + 2] += v.z;
        acc[j + 3] += v.w;
      }
    }
#pragma unroll
    for (int j = 0; j < 32; ++j) ts[ci][c0 + j] = acc[j];
    if ((t & 3) == 0) cf[ci] = (float)(s1 - s0);
  }
  __syncthreads();
  const int lane = t & 63;
  const int w = t >> 6;
  float* ob = out + (long)b * HID * GCELLS + g0 + lane;
  const float cnt = cf[lane];
  const bool nz = cnt > 0.f;
  const float inv = nz ? 1.0f / cnt : 0.f;
#pragma unroll 4
  for (int cc = w; cc < HID; cc += 4) {
    float v = ts[lane][cc] * inv;
    ob[(long)cc * GCELLS] = nz ? v : 0.f;
  }
}

extern "C" void kernel_launch(void* const* d_in, const int* in_sizes, int n_in,
                              void* d_out, int out_size, void* d_ws,
                              size_t ws_size, hipStream_t stream) {
  const float* points = (const float*)d_in[0];
  const int* idx = (const int*)d_in[1];
  const float* fc_pos_w = (const float*)d_in[2];
  const float* fc_pos_b = (const float*)d_in[3];
  const float* fc0_w = (const float*)d_in[4];
  const float* fc0_b = (const float*)d_in[5];
  const float* fc1_w = (const float*)d_in[6];
  const float* fc1_b = (const float*)d_in[7];
  const float* sc_w = (const float*)d_in[8];
  const float* fc_c_w = (const float*)d_in[9];
  const float* fc_c_b = (const float*)d_in[10];
  float* out = (float*)d_out;

  const long NET_BYTES = (long)NROWS * HID * 4;         // 102,400,000
  const long CELL_BYTES = (long)NCELL * HID * 4;        // 33,554,432
  unsigned* net = (unsigned*)d_ws;                      // permuted plane rows
  unsigned* cellf = (unsigned*)((char*)d_ws + NET_BYTES);
  int* offsets = (int*)((char*)d_ws + NET_BYTES + CELL_BYTES);  // 65537 ints

  // scratch in d_out's dead region (overwritten by cellsum_mean at the end)
  unsigned short* packs = (unsigned short*)d_out;
  unsigned short* w0p = packs;            // 5 * 65536
  unsigned short* swp = packs + 327680;   // 5 * 65536
  unsigned short* w1p = packs + 655360;   // 5 * 32768
  unsigned short* wcp = packs + 819200;   // 32768
  int* curs = (int*)((char*)d_out + (2l << 20));
  int* perm = (int*)((char*)d_out + (3l << 20));
  int* vcell = (int*)((char*)d_out + (4l << 20));

  const int GRID_PTS = (NROWS + 255) / 256;       // 782
  const int GRID_ZERO = (NCELL + 255) / 256;      // 256
  const int GRID_CELL = NCELL / 4;                // 16384
  const int GRID_CM = NCELL / 64;                 // 1024

  pack_weights<<<1664, 256, 0, stream>>>(fc0_w, fc1_w, sc_w, fc_c_w, w0p, w1p,
                                         swp, wcp);

  zero_i32<<<GRID_ZERO, 256, 0, stream>>>(curs, NCELL);
  count_csr<<<GRID_PTS, 256, 0, stream>>>(idx, curs);
  scan_csr<<<1, 1024, 0, stream>>>(curs, offsets);
  zero_i32<<<GRID_ZERO, 256, 0, stream>>>(curs, NCELL);
  scatter_csr<<<GRID_PTS, 256, 0, stream>>>(idx, offsets, curs, perm, vcell);

  resblock_mfma<0><<<GRID_RB, 256, 0, stream>>>(
      points, fc_pos_w, fc_pos_b, nullptr, perm, vcell, w0p, fc0_b, w1p,
      fc1_b, swp, net);

  for (int i = 1; i < 5; ++i) {
    pool_csr<<<GRID_CELL, 256, 0, stream>>>(net, offsets, cellf);
    resblock_mfma<1><<<GRID_RB, 256, 0, stream>>>(
        net, nullptr, nullptr, cellf, perm, vcell, w0p + (long)i * 65536,
        fc0_b + i * HID, w1p + (long)i * 32768, fc1_b + i * HID,
        swp + (long)i * 65536, net);
  }

  final_mfma<<<GRID_RB, 256, 0, stream>>>(net, wcp, fc_c_b);
  cellsum_mean<<<GRID_CM, 256, 0, stream>>>((const float*)net, offsets, out);
}